// Round 5
// baseline (140.937 us; speedup 1.0000x reference)
//
#include <hip/hip_runtime.h>
#include <math.h>

#define Bn 2048
#define Dn 512
#define Cn 16384

typedef float v4f __attribute__((ext_vector_type(4)));

#define WAIT_VM4()  asm volatile("s_waitcnt vmcnt(4)" ::: "memory")
#define WAIT_VM0()  asm volatile("s_waitcnt vmcnt(0)" ::: "memory")
#define RAW_BAR()   asm volatile("s_barrier" ::: "memory")

__device__ __forceinline__ void async16(const void* g, void* l) {
  __builtin_amdgcn_global_load_lds(
      (const __attribute__((address_space(1))) char*)g,
      (__attribute__((address_space(3))) char*)l, 16, 0, 0);
}

// ================= prep: wave-per-row norm/scale/fp8-quant =================

__device__ __forceinline__ void prep_load(
    int row, int lane, const float* __restrict__ w, const float* __restrict__ x,
    float4& a, float4& b)
{
  const float* src = (row < Cn) ? (w + (size_t)row * Dn) : (x + (size_t)(row - Cn) * Dn);
  const float4* s4 = (const float4*)src;
  a = s4[lane * 2];
  b = s4[lane * 2 + 1];
}

__device__ __forceinline__ void prep_row_vals(
    int row, int lane, float4 a, float4 b,
    char* __restrict__ wq8, char* __restrict__ xq8,
    float* __restrict__ fscale, float* __restrict__ ysqA, float* __restrict__ yrA,
    float* __restrict__ xsA, float* __restrict__ xrA)
{
  bool isW = row < Cn;
  float ss = a.x * a.x + a.y * a.y + a.z * a.z + a.w * a.w
           + b.x * b.x + b.y * b.y + b.z * b.z + b.w * b.w;
  #pragma unroll
  for (int d = 1; d < 64; d <<= 1) ss += __shfl_xor(ss, d);

  int w0 = __builtin_amdgcn_cvt_pk_fp8_f32(a.x * 16.f, a.y * 16.f, 0, false);
  w0     = __builtin_amdgcn_cvt_pk_fp8_f32(a.z * 16.f, a.w * 16.f, w0, true);
  int w1 = __builtin_amdgcn_cvt_pk_fp8_f32(b.x * 16.f, b.y * 16.f, 0, false);
  w1     = __builtin_amdgcn_cvt_pk_fp8_f32(b.z * 16.f, b.w * 16.f, w1, true);
  char* dst = isW ? (wq8 + (size_t)row * Dn) : (xq8 + (size_t)(row - Cn) * Dn);
  ((int2*)dst)[lane] = make_int2(w0, w1);

  if (lane == 0) {
    if (isW) {
      float n = fmaxf(sqrtf(ss), 1e-7f);
      // fast tanh: t = (e^{2n}-1)/(e^{2n}+1); clamp arg (tanh(10)==1 in fp32)
      float e2 = __expf(2.f * fminf(n, 10.f));
      float t = (e2 - 1.f) * __builtin_amdgcn_rcpf(e2 + 1.f);
      float tc = fminf(t, 0.95f);   // radius clip folded into scale
      fscale[row] = tc / n;
      float ys = tc * tc;
      ysqA[row] = ys;
      yrA[row] = 1.f / (1.f - fminf(ys, 1.f - 1e-5f));
    } else {
      int r = row - Cn;
      xsA[r] = ss;
      xrA[r] = 1.f / (1.f - fminf(ss, 1.f - 1e-5f));
    }
  }
}

// ================= R5 GEMM: 256x256 tile, 8 waves, 4-phase/K-tile schedule =================
// T3+T4 port (proven +28-41% class): per K-tile (BK=64), 4 phases of
//   {ds_read frag quadrant | issue 1 staging round of tile kt+2 -> barrier ->
//    setprio(1) 16 MFMA setprio(0) -> barrier}
// Triple-buffered LDS (3 x 32KB): prefetch distance 2 K-tiles, counted
// vmcnt(4) at K-tile entry (never 0 mid-loop). buf[(kt+2)%3] was last read at
// kt-1; the kt-entry barrier proves all waves drained those reads (each wave's
// MFMA at kt-1 forced lgkmcnt on its ds_reads) -> staging into it is safe.
// vmcnt accounting (uniform across all 512 threads, 4 loads per K-tile, FIFO):
//   entry of kt: outstanding = kt+1's 4 (old) + kt+2's 4 (new) = 8
//   -> vmcnt(4) waits exactly until tile kt+1... no: until the 4 oldest land,
//      i.e. tile kt's loads landed at kt's entry wait one tile earlier; net:
//      at kt entry the oldest 4 are tile kt+1's only after kt's landed -- the
//      wait guarantees everything except the newest 4 (tile kt+2) has landed,
//      which includes tile kt (read now) and is the R0-proven discipline.
// Fragment/staging layout is the harness-verified chunk-XOR scheme extended
// 128->256 rows (XOR key (row>>1)&3 unaffected by the row-base bits).
__device__ __forceinline__ void gemm256_job(
    int job, int tid, char* lds,
    const char* __restrict__ xq8, const char* __restrict__ wq8,
    const float* __restrict__ fscale, const float* __restrict__ ysqA,
    const float* __restrict__ yrA, const float* __restrict__ xsA,
    const float* __restrict__ xrA, float* __restrict__ partials)
{
  const int xcd = job & 7;
  const int loc = job >> 3;
  const int mt  = loc >> 3;            // 0..7   (M tiles of 256)
  const int nt  = (xcd << 3) | (loc & 7);  // 0..63 (N tiles, XCD-banded)
  const int mBase = mt * 256;
  const int nBase = nt * 256;
  const int lane = tid & 63;
  const int wv = tid >> 6;             // 0..7
  const int quad = lane >> 4;
  const int l16 = lane & 15;
  const int waveM = wv >> 2;           // 0..1 -> 128 rows each
  const int waveN = wv & 3;            // 0..3 -> 64 cols each

  v4f acc[8][4];
  #pragma unroll
  for (int i = 0; i < 8; ++i)
    #pragma unroll
    for (int j = 0; j < 4; ++j)
      acc[i][j] = (v4f){0.f, 0.f, 0.f, 0.f};

  // staging: slot s in [0,1024) covers 256 rows x 64B; thread owns s=tid (round a)
  // and s=tid+512 (round b; row +128, same chunk-XOR). A rounds 0-1, B rounds 2-3.
  const int srow = tid >> 2;                         // 0..127
  const int sc = (tid & 3) ^ ((srow >> 1) & 3);      // conflict-free chunk XOR
  const char* gA = xq8 + (size_t)(mBase + srow) * Dn + sc * 16;
  const char* gB = wq8 + (size_t)(nBase + srow) * Dn + sc * 16;
  const int loA0 = tid * 16,          loA1 = tid * 16 + 8192;
  const int loB0 = tid * 16 + 16384,  loB1 = tid * 16 + 24576;

  const int kx = (l16 >> 1) & 3;
  int aoff[2], boff[2];
  #pragma unroll
  for (int s = 0; s < 2; ++s) {
    int chunk = (2 * s + (quad >> 1)) ^ kx;
    aoff[s] = (waveM * 128 + l16) * 64 + chunk * 16 + (quad & 1) * 8;
    boff[s] = 16384 + (waveN * 64 + l16) * 64 + chunk * 16 + (quad & 1) * 8;
  }

  // prologue: tiles 0,1 -> buffers 0,1 (8 loads/thread in flight)
  #pragma unroll
  for (int t = 0; t < 2; ++t) {
    char* buf = lds + t * 32768;
    async16(gA + t * 64,                       buf + loA0);
    async16(gA + (size_t)128 * Dn + t * 64,    buf + loA1);
    async16(gB + t * 64,                       buf + loB0);
    async16(gB + (size_t)128 * Dn + t * 64,    buf + loB1);
  }

  #pragma unroll
  for (int kt = 0; kt < 8; ++kt) {
    char* buf  = lds + (kt % 3) * 32768;
    char* nbuf = lds + ((kt + 2) % 3) * 32768;
    const bool pre = (kt + 2 < 8);
    if (kt < 7) { WAIT_VM4(); } else { WAIT_VM0(); }
    RAW_BAR();  // tile kt visible to all waves; buf[(kt+2)%3] reads drained

    // ---- phase 0: all B-frags (held across phases) + A m={0,1}; stage round 0
    long bf[4][2];
    #pragma unroll
    for (int n = 0; n < 4; ++n)
      #pragma unroll
      for (int s = 0; s < 2; ++s)
        bf[n][s] = *(const long*)(buf + boff[s] + n * 1024);
    long af[2][2];
    #pragma unroll
    for (int m2 = 0; m2 < 2; ++m2)
      #pragma unroll
      for (int s = 0; s < 2; ++s)
        af[m2][s] = *(const long*)(buf + aoff[s] + m2 * 1024);
    if (pre) async16(gA + (kt + 2) * 64, nbuf + loA0);
    __builtin_amdgcn_s_setprio(1);
    #pragma unroll
    for (int s = 0; s < 2; ++s)
      #pragma unroll
      for (int m2 = 0; m2 < 2; ++m2)
        #pragma unroll
        for (int n = 0; n < 4; ++n)
          acc[m2][n] = __builtin_amdgcn_mfma_f32_16x16x32_fp8_fp8(
              af[m2][s], bf[n][s], acc[m2][n], 0, 0, 0);
    __builtin_amdgcn_s_setprio(0);
    RAW_BAR();

    // ---- phases 1..3: A m={2q,2q+1}; stage rounds 1..3
    #pragma unroll
    for (int q = 1; q < 4; ++q) {
      #pragma unroll
      for (int m2 = 0; m2 < 2; ++m2)
        #pragma unroll
        for (int s = 0; s < 2; ++s)
          af[m2][s] = *(const long*)(buf + aoff[s] + (q * 2 + m2) * 1024);
      if (pre) {
        if (q == 1) async16(gA + (size_t)128 * Dn + (kt + 2) * 64, nbuf + loA1);
        if (q == 2) async16(gB + (kt + 2) * 64,                    nbuf + loB0);
        if (q == 3) async16(gB + (size_t)128 * Dn + (kt + 2) * 64, nbuf + loB1);
      }
      RAW_BAR();
      __builtin_amdgcn_s_setprio(1);
      #pragma unroll
      for (int s = 0; s < 2; ++s)
        #pragma unroll
        for (int m2 = 0; m2 < 2; ++m2)
          #pragma unroll
          for (int n = 0; n < 4; ++n)
            acc[q * 2 + m2][n] = __builtin_amdgcn_mfma_f32_16x16x32_fp8_fp8(
                af[m2][s], bf[n][s], acc[q * 2 + m2][n], 0, 0, 0);
      __builtin_amdgcn_s_setprio(0);
      RAW_BAR();
    }
  }

  // epilogue: e^{+64}-scaled partial sums; 1/256 folds the 16x prescale
  float ysqj[4], yrj[4], gj[4];
  #pragma unroll
  for (int n = 0; n < 4; ++n) {
    int col = nBase + waveN * 64 + n * 16 + l16;
    gj[n] = -2.f * fscale[col] * (1.f / 256.f);
    ysqj[n] = ysqA[col];
    yrj[n] = yrA[col];
  }
  #pragma unroll
  for (int m = 0; m < 8; ++m) {
    #pragma unroll
    for (int r = 0; r < 4; ++r) {
      int row = mBase + waveM * 128 + m * 16 + quad * 4 + r;
      float xs = xsA[row];
      float xr2 = 2.f * xrA[row];
      float partial = 0.f;
      if (xs >= 0.99999f) {
        // clipped row (common: ||x||^2 ~ 1.28): z large -> sims~=1/(2z)
        #pragma unroll
        for (int n = 0; n < 4; ++n) {
          float d = fmaxf(fmaf(gj[n], acc[m][n][r], xs + ysqj[n]), 0.f);
          float z = fmaf(d, xr2 * yrj[n], 1.f);
          float u = 64.f * __builtin_amdgcn_rcpf(z);
          partial += fmaf(u, fmaf(0.5f, u, 1.f), 1.f);
        }
      } else {
        #pragma unroll
        for (int n = 0; n < 4; ++n) {
          float d = fmaxf(fmaf(gj[n], acc[m][n][r], xs + ysqj[n]), 0.f);
          float z = fmaf(d, xr2 * yrj[n], 1.f);
          float sq = sqrtf(fmaf(z, z, -1.f));
          float u = 128.f * __builtin_amdgcn_rcpf(z + sq);
          partial += __expf(u);
        }
      }
      partial += __shfl_xor(partial, 1);
      partial += __shfl_xor(partial, 2);
      partial += __shfl_xor(partial, 4);
      partial += __shfl_xor(partial, 8);
      if (l16 == 0) partials[(size_t)row * 256 + nt * 4 + waveN] = partial;
    }
  }
}

// wave-per-row exact fp32 label fix; returns row term (valid on lane 0)
__device__ __forceinline__ float final_row_term(
    int row, int lane,
    const float* __restrict__ x, const float* __restrict__ w,
    const int* __restrict__ labels, const float* __restrict__ fscale,
    const float* __restrict__ ysqA, const float* __restrict__ yrA,
    const float* __restrict__ xsA, const float* __restrict__ xrA,
    const float* __restrict__ partials)
{
  const float* pr = partials + (size_t)row * 256;
  float sum = pr[lane] + pr[lane + 64] + pr[lane + 128] + pr[lane + 192];

  int lab = labels[row];
  const float4* xv = (const float4*)(x + (size_t)row * Dn);
  const float4* wv4 = (const float4*)(w + (size_t)lab * Dn);
  float4 a0 = xv[lane * 2], a1 = xv[lane * 2 + 1];
  float4 b0 = wv4[lane * 2], b1 = wv4[lane * 2 + 1];
  float dot = a0.x * b0.x + a0.y * b0.y + a0.z * b0.z + a0.w * b0.w
            + a1.x * b1.x + a1.y * b1.y + a1.z * b1.z + a1.w * b1.w;
  #pragma unroll
  for (int d = 1; d < 64; d <<= 1) {
    sum += __shfl_xor(sum, d);
    dot += __shfl_xor(dot, d);
  }

  float term = 0.f;
  if (lane == 0) {
    float xy = fscale[lab] * dot;
    float diff = fmaxf(xsA[row] + ysqA[lab] - 2.f * xy, 0.f);
    float z = fmaf(2.f * diff, xrA[row] * yrA[lab], 1.f);
    float sq = sqrtf(fmaf(z, z, -1.f));
    float sims = 1.f / (z + sq);
    float u_lab = 128.f * sims;
    float cosv = fmaf(2.f, sims, -1.f);
    float sine = sqrtf(fmaxf(fmaf(-cosv, cosv, 1.f), 1e-7f));
    float phi = (cosv > -0.8775825619f)
                    ? (cosv * 0.8775825619f - sine * 0.4794255386f)
                    : (cosv - 0.2397127693f);
    float e_lab = __expf(u_lab);
    float e_phi = __expf(fminf(64.f * phi + 64.f, 80.f));
    term = logf(sum - e_lab + e_phi) - 64.f * phi - 64.f;
  }
  return term;
}

// ================= kernels =================

__global__ __launch_bounds__(256) void prep_kernel(
    const float* __restrict__ w, const float* __restrict__ x,
    char* __restrict__ wq8, char* __restrict__ xq8,
    float* __restrict__ fscale, float* __restrict__ ysqA, float* __restrict__ yrA,
    float* __restrict__ xsA, float* __restrict__ xrA)
{
  int row = (blockIdx.x * 256 + threadIdx.x) >> 6;
  int lane = threadIdx.x & 63;
  float4 a, b;
  prep_load(row, lane, w, x, a, b);
  prep_row_vals(row, lane, a, b, wq8, xq8, fscale, ysqA, yrA, xsA, xrA);
}

__global__ __launch_bounds__(512, 2) void gemm_kernel(
    const char* __restrict__ xq8, const char* __restrict__ wq8,
    const float* __restrict__ fscale, const float* __restrict__ ysqA,
    const float* __restrict__ yrA, const float* __restrict__ xsA,
    const float* __restrict__ xrA, float* __restrict__ partials)
{
  extern __shared__ int4 ldsv[];  // 96 KB dynamic: 3 x [A 16K][B 16K]
  gemm256_job(blockIdx.x, threadIdx.x, (char*)ldsv, xq8, wq8,
              fscale, ysqA, yrA, xsA, xrA, partials);
}

__global__ __launch_bounds__(256) void final_kernel(
    const float* __restrict__ x, const float* __restrict__ w,
    const int* __restrict__ labels, const float* __restrict__ fscale,
    const float* __restrict__ ysqA, const float* __restrict__ yrA,
    const float* __restrict__ xsA, const float* __restrict__ xrA,
    const float* __restrict__ partials, float* __restrict__ out)
{
  int row = blockIdx.x * 4 + (threadIdx.x >> 6);
  float term = final_row_term(row, threadIdx.x & 63, x, w, labels, fscale,
                              ysqA, yrA, xsA, xrA, partials);
  __shared__ float red[4];
  if ((threadIdx.x & 63) == 0) red[threadIdx.x >> 6] = term;
  __syncthreads();
  if (threadIdx.x == 0)
    atomicAdd(out, (red[0] + red[1] + red[2] + red[3]) * (1.f / (float)Bn));
}

extern "C" void kernel_launch(void* const* d_in, const int* in_sizes, int n_in,
                              void* d_out, int out_size, void* d_ws, size_t ws_size,
                              hipStream_t stream) {
  (void)in_sizes; (void)n_in; (void)out_size; (void)ws_size;
  const float* emb = (const float*)d_in[0];
  const int* labels = (const int*)d_in[1];
  const float* weight = (const float*)d_in[2];
  float* out = (float*)d_out;

  char* p = (char*)d_ws;
  char* wq8 = p; p += (size_t)Cn * Dn;       // 8 MB fp8
  char* xq8 = p; p += (size_t)Bn * Dn;       // 1 MB fp8
  float* fscale = (float*)p; p += (size_t)Cn * 4;
  float* ysqA  = (float*)p; p += (size_t)Cn * 4;
  float* yrA   = (float*)p; p += (size_t)Cn * 4;
  float* xsA   = (float*)p; p += (size_t)Bn * 4;
  float* xrA   = (float*)p; p += (size_t)Bn * 4;
  float* partials = (float*)p; p += (size_t)Bn * 256 * 4;  // 2 MB, written-once

  hipMemsetAsync(out, 0, sizeof(float), stream);
  prep_kernel<<<(Cn + Bn) / 4, 256, 0, stream>>>(weight, emb, wq8, xq8, fscale, ysqA, yrA, xsA, xrA);
  gemm_kernel<<<(Bn / 256) * (Cn / 256), 512, 3 * 32768, stream>>>(
      xq8, wq8, fscale, ysqA, yrA, xsA, xrA, partials);
  final_kernel<<<Bn / 4, 256, 0, stream>>>(emb, weight, labels, fscale, ysqA, yrA, xsA, xrA, partials, out);
}

// Round 6
// 124.381 us; speedup vs baseline: 1.1331x; 1.1331x over previous
//
#include <hip/hip_runtime.h>
#include <math.h>

#define Bn 2048
#define Dn 512
#define Cn 16384

typedef float v4f __attribute__((ext_vector_type(4)));

#define WAIT_VM4()  asm volatile("s_waitcnt vmcnt(4)" ::: "memory")
#define WAIT_VM0()  asm volatile("s_waitcnt vmcnt(0)" ::: "memory")
#define RAW_BAR()   asm volatile("s_barrier" ::: "memory")
#define LGKM0_BAR() asm volatile("s_waitcnt lgkmcnt(0)\n\ts_barrier" ::: "memory")

__device__ __forceinline__ void async16(const void* g, void* l) {
  __builtin_amdgcn_global_load_lds(
      (const __attribute__((address_space(1))) char*)g,
      (__attribute__((address_space(3))) char*)l, 16, 0, 0);
}

// ================= prep: 4 rows/wave, loads hoisted for MLP =================

__device__ __forceinline__ void prep_load(
    int row, int lane, const float* __restrict__ w, const float* __restrict__ x,
    float4& a, float4& b)
{
  const float* src = (row < Cn) ? (w + (size_t)row * Dn) : (x + (size_t)(row - Cn) * Dn);
  const float4* s4 = (const float4*)src;
  a = s4[lane * 2];
  b = s4[lane * 2 + 1];
}

__device__ __forceinline__ void prep_row_vals(
    int row, int lane, float4 a, float4 b,
    char* __restrict__ wq8, char* __restrict__ xq8,
    float* __restrict__ fscale, float* __restrict__ ysqA, float* __restrict__ yrA,
    float* __restrict__ xsA, float* __restrict__ xrA)
{
  bool isW = row < Cn;
  float ss = a.x * a.x + a.y * a.y + a.z * a.z + a.w * a.w
           + b.x * b.x + b.y * b.y + b.z * b.z + b.w * b.w;
  #pragma unroll
  for (int d = 1; d < 64; d <<= 1) ss += __shfl_xor(ss, d);

  int w0 = __builtin_amdgcn_cvt_pk_fp8_f32(a.x * 16.f, a.y * 16.f, 0, false);
  w0     = __builtin_amdgcn_cvt_pk_fp8_f32(a.z * 16.f, a.w * 16.f, w0, true);
  int w1 = __builtin_amdgcn_cvt_pk_fp8_f32(b.x * 16.f, b.y * 16.f, 0, false);
  w1     = __builtin_amdgcn_cvt_pk_fp8_f32(b.z * 16.f, b.w * 16.f, w1, true);
  char* dst = isW ? (wq8 + (size_t)row * Dn) : (xq8 + (size_t)(row - Cn) * Dn);
  ((int2*)dst)[lane] = make_int2(w0, w1);

  if (lane == 0) {
    if (isW) {
      float n = fmaxf(sqrtf(ss), 1e-7f);
      // fast tanh: t = (e^{2n}-1)/(e^{2n}+1); clamp arg (tanh(10)==1 in fp32)
      float e2 = __expf(2.f * fminf(n, 10.f));
      float t = (e2 - 1.f) * __builtin_amdgcn_rcpf(e2 + 1.f);
      float tc = fminf(t, 0.95f);   // radius clip folded into scale
      fscale[row] = tc / n;
      float ys = tc * tc;
      ysqA[row] = ys;
      yrA[row] = 1.f / (1.f - fminf(ys, 1.f - 1e-5f));
    } else {
      int r = row - Cn;
      xsA[r] = ss;
      xrA[r] = 1.f / (1.f - fminf(ss, 1.f - 1e-5f));
    }
  }
}

// one 128x128 fp8 GEMM job: 2-buffer (32 KB) vmcnt pipeline (R4-proven, reverted)
__device__ __forceinline__ void gemm_job(
    int job, int tid, char* lds,
    const char* __restrict__ xq8, const char* __restrict__ wq8,
    const float* __restrict__ fscale, const float* __restrict__ ysqA,
    const float* __restrict__ yrA, const float* __restrict__ xsA,
    const float* __restrict__ xrA, float* __restrict__ partials)
{
  const int xcd = job & 7;
  const int loc = job >> 3;
  const int mt  = loc & 15;
  const int nt  = (xcd << 4) | (loc >> 4);
  const int mBase = mt * 128;
  const int nBase = nt * 128;
  const int lane = tid & 63;
  const int wv = tid >> 6;
  const int quad = lane >> 4;
  const int l16 = lane & 15;
  const int waveM = wv >> 1;
  const int waveN = wv & 1;

  v4f acc[4][4];
  #pragma unroll
  for (int i = 0; i < 4; ++i)
    #pragma unroll
    for (int j = 0; j < 4; ++j)
      acc[i][j] = (v4f){0.f, 0.f, 0.f, 0.f};

  // staging: slot s -> r=s>>2, global chunk col (s&3)^((r>>1)&3)  (conflict-free)
  const int s0 = tid, s1 = tid + 256;
  const int r0 = s0 >> 2, c0 = (s0 & 3) ^ ((r0 >> 1) & 3);
  const int r1 = s1 >> 2, c1 = (s1 & 3) ^ ((r1 >> 1) & 3);
  const char* gA0 = xq8 + (size_t)(mBase + r0) * Dn + c0 * 16;
  const char* gA1 = xq8 + (size_t)(mBase + r1) * Dn + c1 * 16;
  const char* gW0 = wq8 + (size_t)(nBase + r0) * Dn + c0 * 16;
  const char* gW1 = wq8 + (size_t)(nBase + r1) * Dn + c1 * 16;
  const int lo0 = s0 * 16, lo1 = s1 * 16;

  const int kx = (l16 >> 1) & 3;
  int aoff[2], boff[2];
  #pragma unroll
  for (int s = 0; s < 2; ++s) {
    int chunk = (2 * s + (quad >> 1)) ^ kx;
    aoff[s] = (waveM * 64 + l16) * 64 + chunk * 16 + (quad & 1) * 8;
    boff[s] = (waveN * 64 + l16) * 64 + chunk * 16 + (quad & 1) * 8;
  }

  // prologue: tiles 0,1 -> buffers 0,1 (8 loads in flight)
  #pragma unroll
  for (int t = 0; t < 2; ++t) {
    char* Ab = lds + t * 16384;
    char* Wb = Ab + 8192;
    async16(gA0 + t * 64, Ab + lo0);
    async16(gA1 + t * 64, Ab + lo1);
    async16(gW0 + t * 64, Wb + lo0);
    async16(gW1 + t * 64, Wb + lo1);
  }

  #pragma unroll
  for (int kt = 0; kt < 8; ++kt) {
    const int cur = kt & 1;
    if (kt < 7) { WAIT_VM4(); } else { WAIT_VM0(); }  // tile kt landed (this wave)
    RAW_BAR();                                         // ...for all waves
    char* Ab = lds + cur * 16384;
    char* Wb = Ab + 8192;
    long af[4][2], bf[4][2];
    #pragma unroll
    for (int s = 0; s < 2; ++s) {
      #pragma unroll
      for (int i = 0; i < 4; ++i) af[i][s] = *(const long*)(Ab + aoff[s] + i * 1024);
      #pragma unroll
      for (int j = 0; j < 4; ++j) bf[j][s] = *(const long*)(Wb + boff[s] + j * 1024);
    }
    #pragma unroll
    for (int s = 0; s < 2; ++s)
      #pragma unroll
      for (int i = 0; i < 4; ++i)
        #pragma unroll
        for (int j = 0; j < 4; ++j)
          acc[i][j] = __builtin_amdgcn_mfma_f32_16x16x32_fp8_fp8(af[i][s], bf[j][s], acc[i][j], 0, 0, 0);
    LGKM0_BAR();  // all waves' reads of buf[cur] drained -> safe to rewrite
    if (kt + 2 < 8) {  // tile kt+2 into buf[cur]
      async16(gA0 + (kt + 2) * 64, Ab + lo0);
      async16(gA1 + (kt + 2) * 64, Ab + lo1);
      async16(gW0 + (kt + 2) * 64, Wb + lo0);
      async16(gW1 + (kt + 2) * 64, Wb + lo1);
    }
  }

  // epilogue: e^{+64}-scaled partial sums; 1/256 folds the 16x prescale
  float ysqj[4], yrj[4], gj[4];
  #pragma unroll
  for (int j = 0; j < 4; ++j) {
    int col = nBase + waveN * 64 + j * 16 + l16;
    gj[j] = -2.f * fscale[col] * (1.f / 256.f);
    ysqj[j] = ysqA[col];
    yrj[j] = yrA[col];
  }
  #pragma unroll
  for (int i = 0; i < 4; ++i) {
    #pragma unroll
    for (int r = 0; r < 4; ++r) {
      int row = mBase + waveM * 64 + i * 16 + quad * 4 + r;
      float xs = xsA[row];
      float xr2 = 2.f * xrA[row];
      float partial = 0.f;
      if (xs >= 0.99999f) {
        // clipped row (common: ||x||^2 ~ 1.28): z large -> sims~=1/(2z)
        #pragma unroll
        for (int j = 0; j < 4; ++j) {
          float d = fmaxf(fmaf(gj[j], acc[i][j][r], xs + ysqj[j]), 0.f);
          float z = fmaf(d, xr2 * yrj[j], 1.f);
          float u = 64.f * __builtin_amdgcn_rcpf(z);
          partial += fmaf(u, fmaf(0.5f, u, 1.f), 1.f);
        }
      } else {
        #pragma unroll
        for (int j = 0; j < 4; ++j) {
          float d = fmaxf(fmaf(gj[j], acc[i][j][r], xs + ysqj[j]), 0.f);
          float z = fmaf(d, xr2 * yrj[j], 1.f);
          float sq = sqrtf(fmaf(z, z, -1.f));
          float u = 128.f * __builtin_amdgcn_rcpf(z + sq);
          partial += __expf(u);
        }
      }
      partial += __shfl_xor(partial, 1);
      partial += __shfl_xor(partial, 2);
      partial += __shfl_xor(partial, 4);
      partial += __shfl_xor(partial, 8);
      if (l16 == 0) partials[(size_t)row * 256 + nt * 2 + waveN] = partial;
    }
  }
}

// ================= kernels =================

// prep: 4 consecutive rows per wave; all 8 row-loads issued before any reduce
// (MLP x4), then 4 independent reduce/convert chains (ILP x4). Numerics per
// row identical to the proven wave-per-row version. Also zeroes `out` (folds
// away the memset dispatch; stream order guarantees it precedes final's atomics).
__global__ __launch_bounds__(256) void prep_kernel(
    const float* __restrict__ w, const float* __restrict__ x,
    char* __restrict__ wq8, char* __restrict__ xq8,
    float* __restrict__ fscale, float* __restrict__ ysqA, float* __restrict__ yrA,
    float* __restrict__ xsA, float* __restrict__ xrA, float* __restrict__ out)
{
  if (blockIdx.x == 0 && threadIdx.x == 0) *out = 0.f;
  const int lane = threadIdx.x & 63;
  const int base = (blockIdx.x * 4 + (threadIdx.x >> 6)) * 4;  // wave's first row
  float4 a[4], b[4];
  #pragma unroll
  for (int i = 0; i < 4; ++i) prep_load(base + i, lane, w, x, a[i], b[i]);
  #pragma unroll
  for (int i = 0; i < 4; ++i)
    prep_row_vals(base + i, lane, a[i], b[i], wq8, xq8, fscale, ysqA, yrA, xsA, xrA);
}

__global__ __launch_bounds__(256, 3) void gemm_kernel(
    const char* __restrict__ xq8, const char* __restrict__ wq8,
    const float* __restrict__ fscale, const float* __restrict__ ysqA,
    const float* __restrict__ yrA, const float* __restrict__ xsA,
    const float* __restrict__ xrA, float* __restrict__ partials)
{
  __shared__ int4 ldsv[2048];  // 32 KB: buf{0,1} x [A 8K][W 8K]
  gemm_job(blockIdx.x, threadIdx.x, (char*)ldsv, xq8, wq8, fscale, ysqA, yrA, xsA, xrA, partials);
}

// final: 2 rows per wave, all global loads hoisted ahead of the shuffle
// reduces (partials + labels first, then the label-dependent w rows + x rows);
// 4 independent reduce chains interleave. Per-row math identical.
__global__ __launch_bounds__(256) void final_kernel(
    const float* __restrict__ x, const float* __restrict__ w,
    const int* __restrict__ labels, const float* __restrict__ fscale,
    const float* __restrict__ ysqA, const float* __restrict__ yrA,
    const float* __restrict__ xsA, const float* __restrict__ xrA,
    const float* __restrict__ partials, float* __restrict__ out)
{
  const int lane = threadIdx.x & 63;
  const int wvid = threadIdx.x >> 6;
  const int r0 = (blockIdx.x * 4 + wvid) * 2;
  const int r1 = r0 + 1;

  // hoisted loads
  const int lab0 = labels[r0], lab1 = labels[r1];
  const float* pr0 = partials + (size_t)r0 * 256;
  const float* pr1 = partials + (size_t)r1 * 256;
  float sum0 = pr0[lane] + pr0[lane + 64] + pr0[lane + 128] + pr0[lane + 192];
  float sum1 = pr1[lane] + pr1[lane + 64] + pr1[lane + 128] + pr1[lane + 192];

  const float4* xv0 = (const float4*)(x + (size_t)r0 * Dn);
  const float4* xv1 = (const float4*)(x + (size_t)r1 * Dn);
  const float4* wv0 = (const float4*)(w + (size_t)lab0 * Dn);
  const float4* wv1 = (const float4*)(w + (size_t)lab1 * Dn);
  float4 a00 = xv0[lane * 2], a01 = xv0[lane * 2 + 1];
  float4 b00 = wv0[lane * 2], b01 = wv0[lane * 2 + 1];
  float4 a10 = xv1[lane * 2], a11 = xv1[lane * 2 + 1];
  float4 b10 = wv1[lane * 2], b11 = wv1[lane * 2 + 1];
  float dot0 = a00.x * b00.x + a00.y * b00.y + a00.z * b00.z + a00.w * b00.w
             + a01.x * b01.x + a01.y * b01.y + a01.z * b01.z + a01.w * b01.w;
  float dot1 = a10.x * b10.x + a10.y * b10.y + a10.z * b10.z + a10.w * b10.w
             + a11.x * b11.x + a11.y * b11.y + a11.z * b11.z + a11.w * b11.w;

  #pragma unroll
  for (int d = 1; d < 64; d <<= 1) {
    sum0 += __shfl_xor(sum0, d);
    dot0 += __shfl_xor(dot0, d);
    sum1 += __shfl_xor(sum1, d);
    dot1 += __shfl_xor(dot1, d);
  }

  float term = 0.f;
  if (lane == 0) {
    #pragma unroll
    for (int h = 0; h < 2; ++h) {
      const int row = h ? r1 : r0;
      const int lab = h ? lab1 : lab0;
      const float sum = h ? sum1 : sum0;
      const float dot = h ? dot1 : dot0;
      float xy = fscale[lab] * dot;
      float diff = fmaxf(xsA[row] + ysqA[lab] - 2.f * xy, 0.f);
      float z = fmaf(2.f * diff, xrA[row] * yrA[lab], 1.f);
      float sq = sqrtf(fmaf(z, z, -1.f));
      float sims = 1.f / (z + sq);
      float u_lab = 128.f * sims;
      float cosv = fmaf(2.f, sims, -1.f);
      float sine = sqrtf(fmaxf(fmaf(-cosv, cosv, 1.f), 1e-7f));
      float phi = (cosv > -0.8775825619f)
                      ? (cosv * 0.8775825619f - sine * 0.4794255386f)
                      : (cosv - 0.2397127693f);
      float e_lab = __expf(u_lab);
      float e_phi = __expf(fminf(64.f * phi + 64.f, 80.f));
      term += logf(sum - e_lab + e_phi) - 64.f * phi - 64.f;
    }
  }

  __shared__ float red[4];
  if (lane == 0) red[wvid] = term;
  __syncthreads();
  if (threadIdx.x == 0)
    atomicAdd(out, (red[0] + red[1] + red[2] + red[3]) * (1.f / (float)Bn));
}

extern "C" void kernel_launch(void* const* d_in, const int* in_sizes, int n_in,
                              void* d_out, int out_size, void* d_ws, size_t ws_size,
                              hipStream_t stream) {
  (void)in_sizes; (void)n_in; (void)out_size; (void)ws_size;
  const float* emb = (const float*)d_in[0];
  const int* labels = (const int*)d_in[1];
  const float* weight = (const float*)d_in[2];
  float* out = (float*)d_out;

  char* p = (char*)d_ws;
  char* wq8 = p; p += (size_t)Cn * Dn;       // 8 MB fp8
  char* xq8 = p; p += (size_t)Bn * Dn;       // 1 MB fp8
  float* fscale = (float*)p; p += (size_t)Cn * 4;
  float* ysqA  = (float*)p; p += (size_t)Cn * 4;
  float* yrA   = (float*)p; p += (size_t)Cn * 4;
  float* xsA   = (float*)p; p += (size_t)Bn * 4;
  float* xrA   = (float*)p; p += (size_t)Bn * 4;
  float* partials = (float*)p; p += (size_t)Bn * 256 * 4;  // 2 MB, written-once

  // prep zeroes `out` (stream-ordered before final) — no memset dispatch
  prep_kernel<<<(Cn + Bn) / 16, 256, 0, stream>>>(weight, emb, wq8, xq8, fscale, ysqA, yrA, xsA, xrA, out);
  gemm_kernel<<<(Bn / 128) * (Cn / 128), 256, 0, stream>>>(
      xq8, wq8, fscale, ysqA, yrA, xsA, xrA, partials);
  final_kernel<<<Bn / 8, 256, 0, stream>>>(emb, weight, labels, fscale, ysqA, yrA, xsA, xrA, partials, out);
}